// Round 5
// baseline (245.582 us; speedup 1.0000x reference)
//
#include <hip/hip_runtime.h>
#include <hip/hip_bf16.h>

#define K_CODES 512
#define CDIM    256
#define HW      1024
#define NBATCH  64
#define SZ      260   // fallback kernel LDS stride

typedef float  f32x16 __attribute__((ext_vector_type(16)));
typedef short  bf16x8 __attribute__((ext_vector_type(8)));

__device__ __forceinline__ unsigned short f2bf(float x) {
    unsigned u = __float_as_uint(x);
    unsigned r = (u + 0x7FFFu + ((u >> 16) & 1u)) >> 16;   // RNE
    return (unsigned short)r;
}

// ---------------- Prep: en[512] fp32 + codebook bf16 ----------------
__global__ __launch_bounds__(64) void vq_prep(const float* __restrict__ cb,
                                              float* __restrict__ enorm,
                                              unsigned short* __restrict__ cb16) {
    int k = blockIdx.x;
    int l = threadIdx.x;
    float4 v = *reinterpret_cast<const float4*>(cb + (size_t)k * CDIM + l * 4);
    float s = (v.x * v.x + v.y * v.y) + (v.z * v.z + v.w * v.w);
#pragma unroll
    for (int off = 1; off < 64; off <<= 1) s += __shfl_xor(s, off, 64);
    if (l == 0) enorm[k] = s;
    ushort4 o;
    o.x = f2bf(v.x); o.y = f2bf(v.y); o.z = f2bf(v.z); o.w = f2bf(v.w);
    *reinterpret_cast<ushort4*>(cb16 + (size_t)k * CDIM + l * 4) = o;
}

__global__ __launch_bounds__(64) void vq_enorm(const float* __restrict__ cb,
                                               float* __restrict__ enorm) {
    int k = blockIdx.x;
    int l = threadIdx.x;
    float4 v = *reinterpret_cast<const float4*>(cb + (size_t)k * CDIM + l * 4);
    float s = (v.x * v.x + v.y * v.y) + (v.z * v.z + v.w * v.w);
#pragma unroll
    for (int off = 1; off < 64; off <<= 1) s += __shfl_xor(s, off, 64);
    if (l == 0) enorm[k] = s;
}

// ---------------- Pass 1: single-sweep MFMA filter, 128 rows/block, 2 blocks/CU ----------------
// 4 waves x 32 rows. 18 phases of 32 codes (16 + 2 redo). es double-buffered with
// rotate layout unit' = (u + code) & 31 -> conflict-free b128 a-frag reads.
// Emission: v >= runmax - pad_emit (superset); final prune with validated margin.
#define LOADPH(ph, R) do {                                                              \
    int c0p = ((ph) & 15) << 5;                                                         \
    _Pragma("unroll")                                                                   \
    for (int q = 0; q < 4; ++q) {                                                       \
        int li = (q << 8) + t; int cd = li >> 5; int uu = li & 31;                      \
        int uo = (uu - cd) & 31;                                                        \
        R[q] = *reinterpret_cast<const uint4*>(cb16 + (size_t)((c0p + cd) << 8) + (uo << 3)); \
    } } while (0)

#define STOREPH(bsel, R) do {                                                           \
    unsigned short* eb_ = es + ((bsel) ? 8192 : 0);                                     \
    _Pragma("unroll")                                                                   \
    for (int q = 0; q < 4; ++q) {                                                       \
        int li = (q << 8) + t;                                                          \
        *reinterpret_cast<uint4*>(eb_ + (li << 3)) = R[q];                              \
    } } while (0)

__global__ __launch_bounds__(256, 2) void vq_pass1(const float* __restrict__ z,
                                                   const unsigned short* __restrict__ cb16,
                                                   unsigned* __restrict__ cnt_out,
                                                   unsigned short* __restrict__ codes_out,
                                                   int* __restrict__ idx_out) {
    __shared__ __align__(16) char smem[65536];
    unsigned short* zs    = (unsigned short*)smem;            // transient 64 KB
    unsigned*       zsw   = (unsigned*)smem;
    unsigned short* es    = (unsigned short*)smem;            // reuse: 2 x 16 KB
    unsigned*       cntl  = (unsigned*)(smem + 32768);        // 128 u32
    float*          thrl  = (float*)(smem + 33280);           // 128 f32
    float*          valsl = (float*)(smem + 33792);           // 128*16 f32
    unsigned short* codesl= (unsigned short*)(smem + 41984);  // 128*16 u16

    const int t = threadIdx.x;
    const int l = t & 63, w = t >> 6;          // 4 waves
    const int r0 = blockIdx.x << 7;            // 128 rows/block
    const int b  = r0 >> 10, n0 = r0 & 1023;
    const float* zb = z + (size_t)b * (CDIM * HW);

    // ---- stage z: transpose + bf16 (swizzled, same layout as validated round-4)
#pragma unroll
    for (int p = 0; p < 16; ++p) {
        int lin = (p << 8) + t;
        int c2  = lin >> 5;          // 0..127 (k-pairs)
        int iq  = lin & 31;          // 0..31  (row-quads)
        const float* g0 = zb + (size_t)(2 * c2) * HW + n0 + (iq << 2);
        float4 a  = *reinterpret_cast<const float4*>(g0);
        float4 bb = *reinterpret_cast<const float4*>(g0 + HW);
        int up = (((c2 >> 2) ^ (iq & 7)) << 2) + (c2 & 3);
        const float* ap = &a.x; const float* bp = &bb.x;
#pragma unroll
        for (int j = 0; j < 4; ++j) {
            unsigned pk = (unsigned)f2bf(ap[j]) | ((unsigned)f2bf(bp[j]) << 16);
            zsw[((iq << 2) + j) * 128 + up] = pk;
        }
    }
    __syncthreads();

    // ---- B-frags (z rows) into registers
    const int lrow = l & 31, lh = l >> 5;
    const int lf  = (lrow >> 2) & 7;
    const int row = (w << 5) + lrow;           // 0..127
    bf16x8 zf[16];
#pragma unroll
    for (int s = 0; s < 16; ++s) {
        int u = (2 * s + lh) ^ lf;
        zf[s] = *reinterpret_cast<const bf16x8*>(&zs[row * 256 + (u << 3)]);
    }
    float sa = 0.f;
#pragma unroll
    for (int s = 0; s < 16; ++s)
#pragma unroll
        for (int j = 0; j < 8; ++j)
            sa += fabsf(__uint_as_float(((unsigned)(unsigned short)zf[s][j]) << 16));
    sa += __shfl_xor(sa, 32, 64);

    __syncthreads();   // zs dead -> es/lists may reuse the region

    if (t < 128) cntl[t] = 0;
    uint4 Ra[4], Rb[4];
    LOADPH(0, Ra); LOADPH(1, Rb);
    STOREPH(0, Ra);
    __syncthreads();   // phase 0 visible + cntl init visible

    const float pad_emit = sa * 1.8e-5f + 7.5e-4f;
    float runmax = -3.4e38f;

    for (int p = 0; p < 18; ++p) {
        if (p < 17) { if ((p & 1) == 0) STOREPH(1, Rb); else STOREPH(0, Ra); }
        if (p < 16) { if ((p & 1) == 0) LOADPH(p + 2, Ra); else LOADPH(p + 2, Rb); }
        __syncthreads();   // buf(p&1) holds phase p for everyone

        const unsigned short* eb = es + ((p & 1) ? 8192 : 0);
        const int code0 = (p & 15) << 5;

        f32x16 accA = {0.f,0.f,0.f,0.f,0.f,0.f,0.f,0.f,0.f,0.f,0.f,0.f,0.f,0.f,0.f,0.f};
        f32x16 accB = accA;
#pragma unroll
        for (int s = 0; s < 16; s += 2) {
            int u0 = (2 * s + lh + lrow) & 31;
            int u1 = (2 * s + 2 + lh + lrow) & 31;
            bf16x8 a0 = *reinterpret_cast<const bf16x8*>(&eb[(lrow << 8) + (u0 << 3)]);
            bf16x8 a1 = *reinterpret_cast<const bf16x8*>(&eb[(lrow << 8) + (u1 << 3)]);
            accA = __builtin_amdgcn_mfma_f32_32x32x16_bf16(a0, zf[s],     accA, 0, 0, 0);
            accB = __builtin_amdgcn_mfma_f32_32x32x16_bf16(a1, zf[s + 1], accB, 0, 0, 0);
        }

        float bm = -3.4e38f;
        float v[16];
#pragma unroll
        for (int i = 0; i < 16; ++i) { v[i] = accA[i] + accB[i]; bm = fmaxf(bm, v[i]); }

        if (p >= 2) {
            float thr_e = runmax - pad_emit;
#pragma unroll
            for (int i = 0; i < 16; ++i) {
                if (v[i] >= thr_e) {
                    int code = code0 + (i & 3) + 8 * (i >> 2) + 4 * lh;
                    unsigned pos = atomicAdd(&cntl[row], 1u);
                    if (pos < 16u) {
                        valsl[row * 16 + pos]  = v[i];
                        codesl[row * 16 + pos] = (unsigned short)code;
                    }
                }
            }
        }
        bm = fmaxf(bm, __shfl_xor(bm, 32, 64));
        runmax = fmaxf(runmax, bm);
        __syncthreads();   // all reads of buf(p&1) done before next overwrite
    }

    if (lh == 0) thrl[row] = runmax - (sa * 1.7e-5f + 6.0e-4f);  // validated margin
    __syncthreads();

    if (t < 128) {
        unsigned raw = cntl[t];
        if (raw > 16u) {
            cnt_out[r0 + t] = 17u;   // overflow -> rescore full-scans this row
        } else {
            float tf = thrl[t];
            int kept = 0; unsigned short last = 0;
            for (unsigned e = 0; e < raw; ++e) {
                float vv = valsl[t * 16 + e];
                if (vv >= tf) {
                    unsigned short cc = codesl[t * 16 + e];
                    codes_out[(size_t)(r0 + t) * 16 + kept] = cc;
                    last = cc; ++kept;
                }
            }
            cnt_out[r0 + t] = (unsigned)kept;
            if (kept == 1) idx_out[r0 + t] = (int)last;
        }
    }
}

// ---------------- Pass 2: exact fp32 rescore of multi-candidate rows (validated) ----------------
__global__ __launch_bounds__(256) void vq_rescore(const float* __restrict__ z,
                                                  const float* __restrict__ cb,
                                                  const float* __restrict__ enb,
                                                  const unsigned* __restrict__ cnt_in,
                                                  const unsigned short* __restrict__ codes_in,
                                                  int* __restrict__ idx_out) {
    __shared__ __align__(16) float zst[32 * 256];
    __shared__ float znl[32];
    __shared__ unsigned cntl[32];
    __shared__ unsigned short rows2[32];
    __shared__ int nr2;

    const int t  = threadIdx.x;
    const int r0 = blockIdx.x << 5;
    const int b  = r0 >> 10, n0 = r0 & 1023;
    const float* zb = z + (size_t)b * (CDIM * HW);

#pragma unroll
    for (int p = 0; p < 8; ++p) {
        int c  = (p << 5) + (t >> 3);
        int i0 = (t & 7) << 2;
        float4 v = *reinterpret_cast<const float4*>(zb + (size_t)c * HW + n0 + i0);
        int u = c >> 2, c3 = c & 3;
        const float* vp = &v.x;
#pragma unroll
        for (int j = 0; j < 4; ++j) {
            int rw = i0 + j;
            zst[rw * 256 + ((u ^ ((rw >> 2) & 7)) << 2) + c3] = vp[j];
        }
    }
    if (t == 0) nr2 = 0;
    __syncthreads();

    if (t < 32) {
        float s0 = 0.f, s1 = 0.f, s2 = 0.f, s3 = 0.f;
        int f = (t >> 2) & 7;
        for (int u = 0; u < 64; ++u) {
            float4 v = *reinterpret_cast<const float4*>(&zst[t * 256 + ((u ^ f) << 2)]);
            s0 += v.x * v.x; s1 += v.y * v.y; s2 += v.z * v.z; s3 += v.w * v.w;
        }
        znl[t] = (s0 + s1) + (s2 + s3);
        unsigned c = cnt_in[r0 + t];
        cntl[t] = c;
        if (c != 1u) {
            int p = atomicAdd(&nr2, 1);
            rows2[p] = (unsigned short)t;
        }
    }
    __syncthreads();

    const int w = t >> 6, lane = t & 63;
    const int slot = lane >> 4, j = lane & 15;
    const int n2 = nr2;

    for (int base = w * 4; base < n2; base += 16) {
        int ri = base + slot;
        bool active = (ri < n2);
        int row_l = active ? (int)rows2[ri] : 0;
        unsigned cr = cntl[row_l];
        const float* zp = &zst[row_l * 256];
        const int f = (row_l >> 2) & 7;
        const float zn = znl[row_l];
        unsigned long long pk = 0xFFFFFFFFFFFFFFFFull;

        if (cr <= 16u) {
            if (active && j < (int)cr) {
                int code = (int)codes_in[(size_t)(r0 + row_l) * 16 + j];
                const float* ep = cb + (size_t)code * CDIM;
                float acc = 0.f;
                for (int u = 0; u < 64; ++u) {
                    float4 zv = *reinterpret_cast<const float4*>(&zp[(u ^ f) << 2]);
                    float4 ev = *reinterpret_cast<const float4*>(ep + (u << 2));
                    acc += zv.x * ev.x;   // sequential fp32 FMA chain
                    acc += zv.y * ev.y;   // (identical order to validated kernel)
                    acc += zv.z * ev.z;
                    acc += zv.w * ev.w;
                }
                float d = (zn - 2.0f * acc) + enb[code];
                pk = (((unsigned long long)__float_as_uint(d)) << 32) | (unsigned)code;
            }
        } else if (active) {
            for (int b2 = 0; b2 < 32; ++b2) {
                int code = (b2 << 4) + j;
                const float* ep = cb + (size_t)code * CDIM;
                float acc = 0.f;
                for (int u = 0; u < 64; ++u) {
                    float4 zv = *reinterpret_cast<const float4*>(&zp[(u ^ f) << 2]);
                    float4 ev = *reinterpret_cast<const float4*>(ep + (u << 2));
                    acc += zv.x * ev.x; acc += zv.y * ev.y;
                    acc += zv.z * ev.z; acc += zv.w * ev.w;
                }
                float d = (zn - 2.0f * acc) + enb[code];
                unsigned long long q2 =
                    (((unsigned long long)__float_as_uint(d)) << 32) | (unsigned)code;
                if (q2 < pk) pk = q2;
            }
        }
#pragma unroll
        for (int o = 1; o < 16; o <<= 1) {
            unsigned long long q2 = __shfl_xor(pk, o, 64);
            if (q2 < pk) pk = q2;
        }
        if (active && j == 0)
            idx_out[r0 + row_l] = (int)(unsigned)(pk & 0xFFFFFFFFu);
    }
}

// ---------------- Fallback exact argmin (validated round-2 kernel) ----------------
__global__ __launch_bounds__(512) void vq_argmin(const float* __restrict__ z,
                                                 const float* __restrict__ cb,
                                                 const float* __restrict__ enorm,
                                                 int* __restrict__ out_idx) {
    __shared__ float zs[64][SZ];
    __shared__ float es[64][SZ];
    __shared__ float ens[K_CODES];
    __shared__ float zn[64];
    __shared__ float red_d[64][32];
    __shared__ int   red_i[64][32];

    const int t  = threadIdx.x;
    const int r0 = blockIdx.x * 64;
    const int b  = r0 >> 10;
    const int n0 = r0 & 1023;
    const float* zb = z + (size_t)b * CDIM * HW;

#pragma unroll
    for (int p = 0; p < 8; ++p) {
        int lin = p * 512 + t;
        int c   = lin >> 4;
        int i0  = (lin & 15) << 2;
        float4 v = *reinterpret_cast<const float4*>(zb + (size_t)c * HW + n0 + i0);
        zs[i0 + 0][c] = v.x; zs[i0 + 1][c] = v.y;
        zs[i0 + 2][c] = v.z; zs[i0 + 3][c] = v.w;
    }
    if (t < K_CODES) ens[t] = enorm[t];
    __syncthreads();

    if (t < 64) {
        float s0 = 0.f, s1 = 0.f, s2 = 0.f, s3 = 0.f;
        for (int c = 0; c < CDIM; c += 4) {
            float4 v = *reinterpret_cast<const float4*>(&zs[t][c]);
            s0 += v.x * v.x; s1 += v.y * v.y; s2 += v.z * v.z; s3 += v.w * v.w;
        }
        zn[t] = (s0 + s1) + (s2 + s3);
    }

    const int ty = t >> 5, tx = t & 31, row0 = ty * 4;
    float best_d[4]; int best_i[4];
#pragma unroll
    for (int i = 0; i < 4; ++i) { best_d[i] = 3.4e38f; best_i[i] = 0; }

    for (int K0 = 0; K0 < K_CODES; K0 += 64) {
        __syncthreads();
#pragma unroll
        for (int p = 0; p < 8; ++p) {
            int lin = p * 512 + t;
            int j = lin >> 6, c4 = (lin & 63) << 2;
            *reinterpret_cast<float4*>(&es[j][c4]) =
                *reinterpret_cast<const float4*>(cb + (size_t)(K0 + j) * CDIM + c4);
        }
        __syncthreads();

        float acc[4][2];
#pragma unroll
        for (int i = 0; i < 4; ++i) { acc[i][0] = 0.f; acc[i][1] = 0.f; }
#pragma unroll 4
        for (int k = 0; k < CDIM; k += 4) {
            float4 a0 = *reinterpret_cast<const float4*>(&zs[row0 + 0][k]);
            float4 a1 = *reinterpret_cast<const float4*>(&zs[row0 + 1][k]);
            float4 a2 = *reinterpret_cast<const float4*>(&zs[row0 + 2][k]);
            float4 a3 = *reinterpret_cast<const float4*>(&zs[row0 + 3][k]);
            float4 e0 = *reinterpret_cast<const float4*>(&es[tx][k]);
            float4 e1 = *reinterpret_cast<const float4*>(&es[tx + 32][k]);
            float4 aa[4] = {a0, a1, a2, a3};
#pragma unroll
            for (int i = 0; i < 4; ++i) {
#pragma unroll
                for (int j = 0; j < 2; ++j) {
                    float4 e = j ? e1 : e0;
                    acc[i][j] += aa[i].x * e.x; acc[i][j] += aa[i].y * e.y;
                    acc[i][j] += aa[i].z * e.z; acc[i][j] += aa[i].w * e.w;
                }
            }
        }
#pragma unroll
        for (int i = 0; i < 4; ++i) {
            float zni = zn[row0 + i];
#pragma unroll
            for (int j = 0; j < 2; ++j) {
                int code = K0 + j * 32 + tx;
                float d = (zni - 2.0f * acc[i][j]) + ens[code];
                if (d < best_d[i]) { best_d[i] = d; best_i[i] = code; }
            }
        }
    }
    __syncthreads();
#pragma unroll
    for (int i = 0; i < 4; ++i) {
        red_d[row0 + i][tx] = best_d[i];
        red_i[row0 + i][tx] = best_i[i];
    }
    __syncthreads();
    if (t < 64) {
        float bd = red_d[t][0]; int bi = red_i[t][0];
        for (int x = 1; x < 32; ++x) {
            float d = red_d[t][x]; int ii = red_i[t][x];
            if (d < bd || (d == bd && ii < bi)) { bd = d; bi = ii; }
        }
        out_idx[r0 + t] = bi;
    }
}

// ---------------- Gather + transpose write + index write ----------------
__global__ __launch_bounds__(256) void vq_gather(const float* __restrict__ cb,
                                                 const int* __restrict__ idx,
                                                 float* __restrict__ out) {
    const int blk = blockIdx.x;
    const int b   = blk >> 4;
    const int n0  = (blk & 15) << 6;
    const int t   = threadIdx.x;
    const int n   = t & 63;
    const int c0  = t >> 6;
    const int code = idx[b * HW + n0 + n];
    const float* crow = cb + (size_t)code * CDIM;
    float* ob = out + (size_t)b * CDIM * HW + n0 + n;

    if (c0 == 0)
        out[(size_t)NBATCH * CDIM * HW + (size_t)b * HW + n0 + n] = (float)code;

#pragma unroll 4
    for (int q = 0; q < 64; q += 4) {
        int c = c0 * 64 + q;
        float4 v = *reinterpret_cast<const float4*>(crow + c);
        ob[(size_t)(c + 0) * HW] = v.x;
        ob[(size_t)(c + 1) * HW] = v.y;
        ob[(size_t)(c + 2) * HW] = v.z;
        ob[(size_t)(c + 3) * HW] = v.w;
    }
}

extern "C" void kernel_launch(void* const* d_in, const int* in_sizes, int n_in,
                              void* d_out, int out_size, void* d_ws, size_t ws_size,
                              hipStream_t stream) {
    const float* z  = (const float*)d_in[0];
    const float* cb = (const float*)d_in[1];
    float* out = (float*)d_out;

    // ws layout
    int*            idx   = (int*)d_ws;                                  // 262144 B
    float*          en    = (float*)((char*)d_ws + 262144);              // 2048 B
    unsigned short* cb16  = (unsigned short*)((char*)d_ws + 264192);     // 262144 B
    unsigned*       cnt   = (unsigned*)((char*)d_ws + 526336);           // 262144 B
    unsigned short* codes = (unsigned short*)((char*)d_ws + 788480);     // 2097152 B
    const size_t NEED_FULL = 2885632;

    if (ws_size >= NEED_FULL) {
        vq_prep   <<<dim3(K_CODES), dim3(64),  0, stream>>>(cb, en, cb16);
        vq_pass1  <<<dim3(512),     dim3(256), 0, stream>>>(z, cb16, cnt, codes, idx);
        vq_rescore<<<dim3(2048),    dim3(256), 0, stream>>>(z, cb, en, cnt, codes, idx);
    } else {
        vq_enorm  <<<dim3(K_CODES), dim3(64),  0, stream>>>(cb, en);
        vq_argmin <<<dim3(1024),    dim3(512), 0, stream>>>(z, cb, en, idx);
    }
    vq_gather<<<dim3(1024), dim3(256), 0, stream>>>(cb, idx, out);
}

// Round 6
// 167.728 us; speedup vs baseline: 1.4642x; 1.4642x over previous
//
#include <hip/hip_runtime.h>
#include <hip/hip_bf16.h>

#define K_CODES 512
#define CDIM    256
#define HW      1024
#define NBATCH  64
#define SZ      260   // fallback kernel LDS stride

typedef float  f32x16 __attribute__((ext_vector_type(16)));
typedef short  bf16x8 __attribute__((ext_vector_type(8)));

typedef __attribute__((address_space(1))) const unsigned int gld_src_t;
typedef __attribute__((address_space(3))) unsigned int       gld_dst_t;

__device__ __forceinline__ unsigned short f2bf(float x) {
    unsigned u = __float_as_uint(x);
    unsigned r = (u + 0x7FFFu + ((u >> 16) & 1u)) >> 16;   // RNE
    return (unsigned short)r;
}

// ---------------- Prep: en[512] fp32 + codebook bf16 ----------------
__global__ __launch_bounds__(64) void vq_prep(const float* __restrict__ cb,
                                              float* __restrict__ enorm,
                                              unsigned short* __restrict__ cb16) {
    int k = blockIdx.x;
    int l = threadIdx.x;
    float4 v = *reinterpret_cast<const float4*>(cb + (size_t)k * CDIM + l * 4);
    float s = (v.x * v.x + v.y * v.y) + (v.z * v.z + v.w * v.w);
#pragma unroll
    for (int off = 1; off < 64; off <<= 1) s += __shfl_xor(s, off, 64);
    if (l == 0) enorm[k] = s;
    ushort4 o;
    o.x = f2bf(v.x); o.y = f2bf(v.y); o.z = f2bf(v.z); o.w = f2bf(v.w);
    *reinterpret_cast<ushort4*>(cb16 + (size_t)k * CDIM + l * 4) = o;
}

__global__ __launch_bounds__(64) void vq_enorm(const float* __restrict__ cb,
                                               float* __restrict__ enorm) {
    int k = blockIdx.x;
    int l = threadIdx.x;
    float4 v = *reinterpret_cast<const float4*>(cb + (size_t)k * CDIM + l * 4);
    float s = (v.x * v.x + v.y * v.y) + (v.z * v.z + v.w * v.w);
#pragma unroll
    for (int off = 1; off < 64; off <<= 1) s += __shfl_xor(s, off, 64);
    if (l == 0) enorm[k] = s;
}

// ---------------- Pass 1: single-sweep MFMA filter, reg top-6, async es pipeline ----------------
// 128 rows/block, 256 thr (4 waves x 32 rows). 16 phases of 32 codes.
// es: 4 x 16KB ring, filled by global_load_lds (linear dest) from pre-rotated
// source addresses (content at linear unit q of local code row = orig unit (q-code)&31),
// so a-frag reads use u = (2s+lh+code)&31 (bank-minimal, same values as validated rounds).
__global__ __launch_bounds__(256, 2) void vq_pass1(const float* __restrict__ z,
                                                   const unsigned short* __restrict__ cb16,
                                                   unsigned* __restrict__ cnt_out,
                                                   unsigned short* __restrict__ codes_out,
                                                   int* __restrict__ idx_out) {
    __shared__ __align__(16) char smem[70144];
    unsigned short* zs    = (unsigned short*)smem;            // 64KB transient
    unsigned*       zsw   = (unsigned*)smem;
    unsigned short* es    = (unsigned short*)smem;            // reuse: 4 x 16KB ring
    unsigned short* candl = (unsigned short*)(smem + 65536);  // 128*16 u16
    unsigned*       cntl  = (unsigned*)(smem + 69632);        // 128 u32

    const int t = threadIdx.x;
    const int l = t & 63, w = t >> 6;          // 4 waves
    const int r0 = blockIdx.x << 7;            // 128 rows/block
    const int b  = r0 >> 10, n0 = r0 & 1023;
    const float* zb = z + (size_t)b * (CDIM * HW);

    // ---- stage z: transpose + bf16 (identical bit-path to validated rounds)
#pragma unroll
    for (int p = 0; p < 16; ++p) {
        int lin = (p << 8) + t;
        int c2  = lin >> 5;          // 0..127 (k-pairs)
        int iq  = lin & 31;          // 0..31  (row-quads)
        const float* g0 = zb + (size_t)(2 * c2) * HW + n0 + (iq << 2);
        float4 a  = *reinterpret_cast<const float4*>(g0);
        float4 bb = *reinterpret_cast<const float4*>(g0 + HW);
        int up = (((c2 >> 2) ^ (iq & 7)) << 2) + (c2 & 3);
        const float* ap = &a.x; const float* bp = &bb.x;
#pragma unroll
        for (int j = 0; j < 4; ++j) {
            unsigned pk = (unsigned)f2bf(ap[j]) | ((unsigned)f2bf(bp[j]) << 16);
            zsw[((iq << 2) + j) * 128 + up] = pk;
        }
    }
    __syncthreads();

    // ---- B-frags (z rows) into registers (identical to validated rounds)
    const int lrow = l & 31, lh = l >> 5;
    const int lf  = (lrow >> 2) & 7;
    const int row = (w << 5) + lrow;           // 0..127
    bf16x8 zf[16];
#pragma unroll
    for (int s = 0; s < 16; ++s) {
        int u = (2 * s + lh) ^ lf;
        zf[s] = *reinterpret_cast<const bf16x8*>(&zs[row * 256 + (u << 3)]);
    }
    float sa = 0.f;
#pragma unroll
    for (int s = 0; s < 16; ++s)
#pragma unroll
        for (int j = 0; j < 8; ++j)
            sa += fabsf(__uint_as_float(((unsigned)(unsigned short)zf[s][j]) << 16));
    sa += __shfl_xor(sa, 32, 64);

    __syncthreads();   // all zs reads done -> es ring may reuse region

    // ---- async es stager: wave w fills chunks w*4..w*4+3 (1KB each) of a phase
    const int lq = l & 31, lhh = l >> 5;
    auto ISSUE = [&](int ph) {
#pragma unroll
        for (int j = 0; j < 4; ++j) {
            int chunk = (w << 2) + j;
            int lc    = (chunk << 1) + lhh;        // local code 0..31
            int su    = (lq - lc) & 31;            // pre-rotated source unit
            const unsigned short* gp = cb16 + (((size_t)((ph << 5) + lc)) << 8) + (su << 3);
            char* lp = smem + (((ph & 3) << 14) + (chunk << 10));
            __builtin_amdgcn_global_load_lds((gld_src_t*)gp, (gld_dst_t*)lp, 16, 0, 0);
        }
    };

    ISSUE(0); ISSUE(1);
    asm volatile("s_waitcnt vmcnt(4)" ::: "memory");
    __builtin_amdgcn_s_barrier();

    const float padf = sa * 1.7e-5f + 6.0e-4f;     // validated margin
    float runmax = -3.4e38f;
    float s0 = -3.4e38f, s1 = -3.4e38f, s2 = -3.4e38f,
          s3 = -3.4e38f, s4 = -3.4e38f, s5 = -3.4e38f;
    int   k0 = 0, k1 = 0, k2 = 0, k3 = 0, k4 = 0, k5 = 0;

    for (int p = 0; p < 16; ++p) {
        if (p + 2 < 16) ISSUE(p + 2);
        if (p >= 1) {
            if (p < 14)       asm volatile("s_waitcnt vmcnt(8)" ::: "memory");
            else if (p == 14) asm volatile("s_waitcnt vmcnt(4)" ::: "memory");
            else              asm volatile("s_waitcnt vmcnt(0)" ::: "memory");
            __builtin_amdgcn_s_barrier();
        }
        const unsigned short* eb = es + ((p & 3) << 13);

        f32x16 accA = {0.f,0.f,0.f,0.f,0.f,0.f,0.f,0.f,0.f,0.f,0.f,0.f,0.f,0.f,0.f,0.f};
        f32x16 accB = accA;
#pragma unroll
        for (int s = 0; s < 16; s += 2) {
            int u0 = (2 * s + lh + lrow) & 31;
            int u1 = (2 * s + 2 + lh + lrow) & 31;
            bf16x8 a0 = *reinterpret_cast<const bf16x8*>(&eb[(lrow << 8) + (u0 << 3)]);
            bf16x8 a1 = *reinterpret_cast<const bf16x8*>(&eb[(lrow << 8) + (u1 << 3)]);
            accA = __builtin_amdgcn_mfma_f32_32x32x16_bf16(a0, zf[s],     accA, 0, 0, 0);
            accB = __builtin_amdgcn_mfma_f32_32x32x16_bf16(a1, zf[s + 1], accB, 0, 0, 0);
        }

        float v[16]; float pm = -3.4e38f;
#pragma unroll
        for (int i = 0; i < 16; ++i) { v[i] = accA[i] + accB[i]; pm = fmaxf(pm, v[i]); }

        // gate is conservative: lane running max <= final rowmax, so any phase
        // containing a final candidate passes. Top-6 by value is maturity-immune.
        if (pm >= runmax - padf) {
            int cbase = (p << 5) + 4 * lh;
#pragma unroll
            for (int i = 0; i < 16; ++i) {
                float vv = v[i];
                int   cc = cbase + (i & 3) + 8 * (i >> 2);
                bool c5 = vv > s5, c4 = vv > s4, c3 = vv > s3,
                     c2 = vv > s2, c1 = vv > s1, c0 = vv > s0;
                s5 = c5 ? (c4 ? s4 : vv) : s5;  k5 = c5 ? (c4 ? k4 : cc) : k5;
                s4 = c4 ? (c3 ? s3 : vv) : s4;  k4 = c4 ? (c3 ? k3 : cc) : k4;
                s3 = c3 ? (c2 ? s2 : vv) : s3;  k3 = c3 ? (c2 ? k2 : cc) : k3;
                s2 = c2 ? (c1 ? s1 : vv) : s2;  k2 = c2 ? (c1 ? k1 : cc) : k2;
                s1 = c1 ? (c0 ? s0 : vv) : s1;  k1 = c1 ? (c0 ? k0 : cc) : k1;
                s0 = c0 ? vv : s0;              k0 = c0 ? cc : k0;
            }
        }
        runmax = fmaxf(runmax, pm);
    }

    // ---- extraction: merge lane pair (lh 0/1), filter by final threshold
    float rowmax = fmaxf(runmax, __shfl_xor(runmax, 32, 64));
    const float thr = rowmax - padf;
    float p0 = __shfl_xor(s0, 32, 64), p1 = __shfl_xor(s1, 32, 64),
          p2 = __shfl_xor(s2, 32, 64), p3 = __shfl_xor(s3, 32, 64),
          p4 = __shfl_xor(s4, 32, 64), p5 = __shfl_xor(s5, 32, 64);
    int   q0 = __shfl_xor(k0, 32, 64), q1 = __shfl_xor(k1, 32, 64),
          q2 = __shfl_xor(k2, 32, 64), q3 = __shfl_xor(k3, 32, 64),
          q4 = __shfl_xor(k4, 32, 64), q5 = __shfl_xor(k5, 32, 64);

    if (lh == 0) {
        int cnt = 0;
#define VQ_EMIT(SV, KV) do { if ((SV) >= thr) { candl[(row << 4) + cnt] = (unsigned short)(KV); ++cnt; } } while (0)
        VQ_EMIT(s0, k0); VQ_EMIT(s1, k1); VQ_EMIT(s2, k2);
        VQ_EMIT(s3, k3); VQ_EMIT(s4, k4); VQ_EMIT(s5, k5);
        VQ_EMIT(p0, q0); VQ_EMIT(p1, q1); VQ_EMIT(p2, q2);
        VQ_EMIT(p3, q3); VQ_EMIT(p4, q4); VQ_EMIT(p5, q5);
#undef VQ_EMIT
        bool of = (s5 >= thr) || (p5 >= thr);   // possible 7th candidate in a lane
        cntl[row] = of ? 17u : (unsigned)cnt;
    }
    __syncthreads();

    if (t < 128) {
        unsigned c = cntl[t];
        cnt_out[r0 + t] = c;
        if (c == 1u) idx_out[r0 + t] = (int)candl[t << 4];
    }
    reinterpret_cast<uint4*>(codes_out + ((size_t)r0 << 4))[t] =
        reinterpret_cast<const uint4*>(candl)[t];
}

// ---------------- Pass 2: exact fp32 rescore of multi-candidate rows ----------------
__global__ __launch_bounds__(256) void vq_rescore(const float* __restrict__ z,
                                                  const float* __restrict__ cb,
                                                  const float* __restrict__ enb,
                                                  const unsigned* __restrict__ cnt_in,
                                                  const unsigned short* __restrict__ codes_in,
                                                  int* __restrict__ idx_out) {
    __shared__ __align__(16) float zst[32 * 256];
    __shared__ float znl[32];
    __shared__ unsigned cntl[32];
    __shared__ unsigned short rows2[32];
    __shared__ unsigned short rowsOF[32];
    __shared__ int nr2, nOF;
    __shared__ unsigned long long ofbest;

    const int t  = threadIdx.x;
    const int r0 = blockIdx.x << 5;
    const int b  = r0 >> 10, n0 = r0 & 1023;
    const float* zb = z + (size_t)b * (CDIM * HW);

    // stage z fp32 transposed, swizzled (identical to validated rounds)
#pragma unroll
    for (int p = 0; p < 8; ++p) {
        int c  = (p << 5) + (t >> 3);
        int i0 = (t & 7) << 2;
        float4 v = *reinterpret_cast<const float4*>(zb + (size_t)c * HW + n0 + i0);
        int u = c >> 2, c3 = c & 3;
        const float* vp = &v.x;
#pragma unroll
        for (int j = 0; j < 4; ++j) {
            int rw = i0 + j;
            zst[rw * 256 + ((u ^ ((rw >> 2) & 7)) << 2) + c3] = vp[j];
        }
    }
    if (t == 0) { nr2 = 0; nOF = 0; }
    __syncthreads();

    if (t < 32) {
        float a0 = 0.f, a1 = 0.f, a2 = 0.f, a3 = 0.f;
        int f = (t >> 2) & 7;
        for (int u = 0; u < 64; ++u) {
            float4 v = *reinterpret_cast<const float4*>(&zst[t * 256 + ((u ^ f) << 2)]);
            a0 += v.x * v.x; a1 += v.y * v.y; a2 += v.z * v.z; a3 += v.w * v.w;
        }
        znl[t] = (a0 + a1) + (a2 + a3);
        unsigned c = cnt_in[r0 + t];
        cntl[t] = c;
        if (c >= 2u && c <= 16u) { int p = atomicAdd(&nr2, 1); rows2[p] = (unsigned short)t; }
        else if (c > 16u)        { int p = atomicAdd(&nOF, 1); rowsOF[p] = (unsigned short)t; }
    }
    __syncthreads();

    const int w = t >> 6, lane = t & 63;
    const int slot = lane >> 4, j = lane & 15;
    const int n2 = nr2;

    for (int base = w * 4; base < n2; base += 16) {
        int ri = base + slot;
        bool active = (ri < n2);
        int row_l = active ? (int)rows2[ri] : 0;
        unsigned cr = cntl[row_l];
        const float* zp = &zst[row_l * 256];
        const int f = (row_l >> 2) & 7;
        const float zn = znl[row_l];
        unsigned long long pk = 0xFFFFFFFFFFFFFFFFull;

        if (active && j < (int)cr) {
            int code = (int)codes_in[(size_t)(r0 + row_l) * 16 + j];
            const float* ep = cb + (size_t)code * CDIM;
            float acc = 0.f;
            for (int u = 0; u < 64; ++u) {
                float4 zv = *reinterpret_cast<const float4*>(&zp[(u ^ f) << 2]);
                float4 ev = *reinterpret_cast<const float4*>(ep + (u << 2));
                acc += zv.x * ev.x;   // sequential fp32 FMA chain
                acc += zv.y * ev.y;   // (identical order to validated kernel)
                acc += zv.z * ev.z;
                acc += zv.w * ev.w;
            }
            float d = (zn - 2.0f * acc) + enb[code];
            pk = (((unsigned long long)__float_as_uint(d)) << 32) | (unsigned)code;
        }
#pragma unroll
        for (int o = 1; o < 16; o <<= 1) {
            unsigned long long q2 = __shfl_xor(pk, o, 64);
            if (q2 < pk) pk = q2;
        }
        if (active && j == 0)
            idx_out[r0 + row_l] = (int)(unsigned)(pk & 0xFFFFFFFFu);
    }

    // overflow rows (cnt==17, ~never): block-wide exact 512-code scan
    const int nof = nOF;
    for (int e = 0; e < nof; ++e) {
        int rw = (int)rowsOF[e];
        if (t == 0) ofbest = 0xFFFFFFFFFFFFFFFFull;
        __syncthreads();
        const float* zp = &zst[rw * 256];
        const int f = (rw >> 2) & 7;
        const float zn = znl[rw];
        unsigned long long pk = 0xFFFFFFFFFFFFFFFFull;
#pragma unroll
        for (int h = 0; h < 2; ++h) {
            int code = (h << 8) + t;
            const float* ep = cb + (size_t)code * CDIM;
            float acc = 0.f;
            for (int u = 0; u < 64; ++u) {
                float4 zv = *reinterpret_cast<const float4*>(&zp[(u ^ f) << 2]);
                float4 ev = *reinterpret_cast<const float4*>(ep + (u << 2));
                acc += zv.x * ev.x; acc += zv.y * ev.y;
                acc += zv.z * ev.z; acc += zv.w * ev.w;
            }
            float d = (zn - 2.0f * acc) + enb[code];
            unsigned long long q2 =
                (((unsigned long long)__float_as_uint(d)) << 32) | (unsigned)code;
            if (q2 < pk) pk = q2;
        }
        atomicMin(&ofbest, pk);
        __syncthreads();
        if (t == 0) idx_out[r0 + rw] = (int)(unsigned)(ofbest & 0xFFFFFFFFu);
    }
}

// ---------------- Fallback exact argmin (validated round-2 kernel) ----------------
__global__ __launch_bounds__(512) void vq_argmin(const float* __restrict__ z,
                                                 const float* __restrict__ cb,
                                                 const float* __restrict__ enorm,
                                                 int* __restrict__ out_idx) {
    __shared__ float zs[64][SZ];
    __shared__ float es[64][SZ];
    __shared__ float ens[K_CODES];
    __shared__ float zn[64];
    __shared__ float red_d[64][32];
    __shared__ int   red_i[64][32];

    const int t  = threadIdx.x;
    const int r0 = blockIdx.x * 64;
    const int b  = r0 >> 10;
    const int n0 = r0 & 1023;
    const float* zb = z + (size_t)b * CDIM * HW;

#pragma unroll
    for (int p = 0; p < 8; ++p) {
        int lin = p * 512 + t;
        int c   = lin >> 4;
        int i0  = (lin & 15) << 2;
        float4 v = *reinterpret_cast<const float4*>(zb + (size_t)c * HW + n0 + i0);
        zs[i0 + 0][c] = v.x; zs[i0 + 1][c] = v.y;
        zs[i0 + 2][c] = v.z; zs[i0 + 3][c] = v.w;
    }
    if (t < K_CODES) ens[t] = enorm[t];
    __syncthreads();

    if (t < 64) {
        float s0 = 0.f, s1 = 0.f, s2 = 0.f, s3 = 0.f;
        for (int c = 0; c < CDIM; c += 4) {
            float4 v = *reinterpret_cast<const float4*>(&zs[t][c]);
            s0 += v.x * v.x; s1 += v.y * v.y; s2 += v.z * v.z; s3 += v.w * v.w;
        }
        zn[t] = (s0 + s1) + (s2 + s3);
    }

    const int ty = t >> 5, tx = t & 31, row0 = ty * 4;
    float best_d[4]; int best_i[4];
#pragma unroll
    for (int i = 0; i < 4; ++i) { best_d[i] = 3.4e38f; best_i[i] = 0; }

    for (int K0 = 0; K0 < K_CODES; K0 += 64) {
        __syncthreads();
#pragma unroll
        for (int p = 0; p < 8; ++p) {
            int lin = p * 512 + t;
            int j = lin >> 6, c4 = (lin & 63) << 2;
            *reinterpret_cast<float4*>(&es[j][c4]) =
                *reinterpret_cast<const float4*>(cb + (size_t)(K0 + j) * CDIM + c4);
        }
        __syncthreads();

        float acc[4][2];
#pragma unroll
        for (int i = 0; i < 4; ++i) { acc[i][0] = 0.f; acc[i][1] = 0.f; }
#pragma unroll 4
        for (int k = 0; k < CDIM; k += 4) {
            float4 a0 = *reinterpret_cast<const float4*>(&zs[row0 + 0][k]);
            float4 a1 = *reinterpret_cast<const float4*>(&zs[row0 + 1][k]);
            float4 a2 = *reinterpret_cast<const float4*>(&zs[row0 + 2][k]);
            float4 a3 = *reinterpret_cast<const float4*>(&zs[row0 + 3][k]);
            float4 e0 = *reinterpret_cast<const float4*>(&es[tx][k]);
            float4 e1 = *reinterpret_cast<const float4*>(&es[tx + 32][k]);
            float4 aa[4] = {a0, a1, a2, a3};
#pragma unroll
            for (int i = 0; i < 4; ++i) {
#pragma unroll
                for (int j = 0; j < 2; ++j) {
                    float4 e = j ? e1 : e0;
                    acc[i][j] += aa[i].x * e.x; acc[i][j] += aa[i].y * e.y;
                    acc[i][j] += aa[i].z * e.z; acc[i][j] += aa[i].w * e.w;
                }
            }
        }
#pragma unroll
        for (int i = 0; i < 4; ++i) {
            float zni = zn[row0 + i];
#pragma unroll
            for (int j = 0; j < 2; ++j) {
                int code = K0 + j * 32 + tx;
                float d = (zni - 2.0f * acc[i][j]) + ens[code];
                if (d < best_d[i]) { best_d[i] = d; best_i[i] = code; }
            }
        }
    }
    __syncthreads();
#pragma unroll
    for (int i = 0; i < 4; ++i) {
        red_d[row0 + i][tx] = best_d[i];
        red_i[row0 + i][tx] = best_i[i];
    }
    __syncthreads();
    if (t < 64) {
        float bd = red_d[t][0]; int bi = red_i[t][0];
        for (int x = 1; x < 32; ++x) {
            float d = red_d[t][x]; int ii = red_i[t][x];
            if (d < bd || (d == bd && ii < bi)) { bd = d; bi = ii; }
        }
        out_idx[r0 + t] = bi;
    }
}

// ---------------- Gather: float4 stores, 1024 blocks ----------------
__global__ __launch_bounds__(256) void vq_gather(const float* __restrict__ cb,
                                                 const int* __restrict__ idx,
                                                 float* __restrict__ out) {
    const int blk = blockIdx.x;
    const int b = blk >> 4;
    const int q = blk & 15;
    const int t = threadIdx.x;
    int4 cd = reinterpret_cast<const int4*>(idx + (b << 10))[t];
    if (q == 0) {
        float4 f = make_float4((float)cd.x, (float)cd.y, (float)cd.z, (float)cd.w);
        reinterpret_cast<float4*>(out + (size_t)NBATCH * CDIM * HW + ((size_t)b << 10))[t] = f;
    }
    const int c0 = q << 4;
    const float* e0 = cb + (size_t)cd.x * CDIM + c0;
    const float* e1 = cb + (size_t)cd.y * CDIM + c0;
    const float* e2 = cb + (size_t)cd.z * CDIM + c0;
    const float* e3 = cb + (size_t)cd.w * CDIM + c0;
    float* ob = out + ((size_t)b * CDIM + c0) * HW + (t << 2);
#pragma unroll 4
    for (int c = 0; c < 16; ++c) {
        float4 v = make_float4(e0[c], e1[c], e2[c], e3[c]);
        *reinterpret_cast<float4*>(ob) = v;
        ob += HW;
    }
}

extern "C" void kernel_launch(void* const* d_in, const int* in_sizes, int n_in,
                              void* d_out, int out_size, void* d_ws, size_t ws_size,
                              hipStream_t stream) {
    const float* z  = (const float*)d_in[0];
    const float* cb = (const float*)d_in[1];
    float* out = (float*)d_out;

    // ws layout
    int*            idx   = (int*)d_ws;                                  // 262144 B
    float*          en    = (float*)((char*)d_ws + 262144);              // 2048 B
    unsigned short* cb16  = (unsigned short*)((char*)d_ws + 264192);     // 262144 B
    unsigned*       cnt   = (unsigned*)((char*)d_ws + 526336);           // 262144 B
    unsigned short* codes = (unsigned short*)((char*)d_ws + 788480);     // 2097152 B
    const size_t NEED_FULL = 2885632;

    if (ws_size >= NEED_FULL) {
        vq_prep   <<<dim3(K_CODES), dim3(64),  0, stream>>>(cb, en, cb16);
        vq_pass1  <<<dim3(512),     dim3(256), 0, stream>>>(z, cb16, cnt, codes, idx);
        vq_rescore<<<dim3(2048),    dim3(256), 0, stream>>>(z, cb, en, cnt, codes, idx);
    } else {
        vq_enorm  <<<dim3(K_CODES), dim3(64),  0, stream>>>(cb, en);
        vq_argmin <<<dim3(1024),    dim3(512), 0, stream>>>(z, cb, en, idx);
    }
    vq_gather<<<dim3(1024), dim3(256), 0, stream>>>(cb, idx, out);
}